// Round 1
// baseline (214.095 us; speedup 1.0000x reference)
//
#include <hip/hip_runtime.h>
#include <hip/hip_bf16.h>
#include <cstdint>

// Problem constants
// B=4, S=2048, E=1024, H=16, D=64, SCALE = 1/8
#define SCALE_F 0.125f

typedef __attribute__((ext_vector_type(8))) short bf16x8;
typedef __attribute__((ext_vector_type(4))) float f32x4;
typedef __attribute__((ext_vector_type(4))) unsigned short u16x4;

typedef const __attribute__((address_space(1))) void glb_void;
typedef __attribute__((address_space(3))) void lds_void;

static __device__ __forceinline__ unsigned short f2bf(float f) {
  unsigned u = __builtin_bit_cast(unsigned, f);
  u = (u + 0x7fffu + ((u >> 16) & 1u)) >> 16;
  return (unsigned short)u;
}

// ---------------- converts ----------------
__global__ __launch_bounds__(256) void cvt_plain(const float* __restrict__ in,
                                                 unsigned short* __restrict__ out, long n) {
  long i = ((long)blockIdx.x * blockDim.x + threadIdx.x) * 4;
  long stride = (long)gridDim.x * blockDim.x * 4;
  for (; i < n; i += stride) {
    float4 v = *(const float4*)(in + i);
    u16x4 o = { f2bf(v.x), f2bf(v.y), f2bf(v.z), f2bf(v.w) };
    *(u16x4*)(out + i) = o;
  }
}

// wq[h*64+d][:] = wqkv[h*192+d][:]
__global__ __launch_bounds__(256) void cvt_wq(const float* __restrict__ wqkv,
                                              unsigned short* __restrict__ wq) {
  int row = blockIdx.x;            // 0..1023
  int h = row >> 6, d = row & 63;
  const float* src = wqkv + (size_t)(h * 192 + d) * 1024 + threadIdx.x * 4;
  unsigned short* dst = wq + (size_t)row * 1024 + threadIdx.x * 4;
  float4 v = *(const float4*)src;
  u16x4 o = { f2bf(v.x), f2bf(v.y), f2bf(v.z), f2bf(v.w) };
  *(u16x4*)dst = o;
}

// wkv[h*128+r][:] = wqkv[h*192+64+r][:]   (r<64: K-dims, r>=64: V-dims)
__global__ __launch_bounds__(256) void cvt_wkv(const float* __restrict__ wqkv,
                                               unsigned short* __restrict__ wkv) {
  int row = blockIdx.x;            // 0..2047
  int h = row >> 7, r = row & 127;
  const float* src = wqkv + (size_t)(h * 192 + 64 + r) * 1024 + threadIdx.x * 4;
  unsigned short* dst = wkv + (size_t)row * 1024 + threadIdx.x * 4;
  float4 v = *(const float4*)src;
  u16x4 o = { f2bf(v.x), f2bf(v.y), f2bf(v.z), f2bf(v.w) };
  *(u16x4*)dst = o;
}

// ---------------- m97-style bt GEMM: C[M][N] = A[M][K] * B[N][K]^T ----------------
template<bool F32OUT>
__global__ __launch_bounds__(256) void gemm_bt(const unsigned short* __restrict__ A,
                                               const unsigned short* __restrict__ Bm,
                                               void* __restrict__ Cv,
                                               int M, int N, int K) {
  __shared__ __align__(16) unsigned short Ash[128 * 32];
  __shared__ __align__(16) unsigned short Bsh[128 * 32];
  const int t = threadIdx.x;
  const int w = t >> 6, l = t & 63;
  const int lr = l & 15, lk = l >> 4;
  const int m0 = blockIdx.y * 128, n0 = blockIdx.x * 128;
  const int wr = (w >> 1) * 64, wc = (w & 1) * 64;
  f32x4 acc[4][4] = {};

  for (int k0 = 0; k0 < K; k0 += 32) {
#pragma unroll
    for (int i = 0; i < 2; ++i) {
      const int c = i * 256 + t;
      const int row = c >> 2, kc = (c & 3) << 3;
      __builtin_amdgcn_global_load_lds(
          (glb_void*)(A + (size_t)(m0 + row) * K + k0 + kc),
          (lds_void*)(Ash + i * 2048 + w * 512), 16, 0, 0);
      __builtin_amdgcn_global_load_lds(
          (glb_void*)(Bm + (size_t)(n0 + row) * K + k0 + kc),
          (lds_void*)(Bsh + i * 2048 + w * 512), 16, 0, 0);
    }
    __syncthreads();   // drains vmcnt(0): staged tiles visible to all waves

    bf16x8 af[4], bfv[4];
#pragma unroll
    for (int mi = 0; mi < 4; ++mi)
      af[mi] = *(const bf16x8*)(Ash + (wr + mi * 16 + lr) * 32 + lk * 8);
#pragma unroll
    for (int ni = 0; ni < 4; ++ni)
      bfv[ni] = *(const bf16x8*)(Bsh + (wc + ni * 16 + lr) * 32 + lk * 8);
#pragma unroll
    for (int mi = 0; mi < 4; ++mi)
#pragma unroll
      for (int ni = 0; ni < 4; ++ni)
        acc[mi][ni] = __builtin_amdgcn_mfma_f32_16x16x32_bf16(af[mi], bfv[ni], acc[mi][ni], 0, 0, 0);
    __syncthreads();   // everyone done reading LDS before next stage
  }

#pragma unroll
  for (int mi = 0; mi < 4; ++mi)
#pragma unroll
    for (int ni = 0; ni < 4; ++ni)
#pragma unroll
      for (int r = 0; r < 4; ++r) {
        const size_t row = (size_t)(m0 + wr + mi * 16 + lk * 4 + r);
        const size_t col = (size_t)(n0 + wc + ni * 16 + lr);
        if constexpr (F32OUT)
          ((float*)Cv)[row * N + col] = acc[mi][ni][r];
        else
          ((unsigned short*)Cv)[row * N + col] = f2bf(acc[mi][ni][r]);
      }
}

// ---------------- fused reassociated attention ----------------
// per (b,h): M64 = K^T V (summed over s=0..2047), then values = SCALE * Q * M64
// Qbuf: [8192][1024] bf16 (token-major, col = h*64+d)
// KVt : [2048][8192] bf16 (row = h*128 + r; r<64 K-dim d=r, r>=64 V-dim d=r-64; col = b*2048+s)
// Vals: [8192][1024] bf16
__global__ __launch_bounds__(512) void attn_fused(const unsigned short* __restrict__ Qbuf,
                                                  const unsigned short* __restrict__ KVt,
                                                  unsigned short* __restrict__ Vals) {
  __shared__ __align__(16) float Msh[64][64];
  __shared__ __align__(16) unsigned short Mt[64][64];  // Mt[n][k] = SCALE*M[k][n], bf16
  const int t = threadIdx.x;
  const int w = t >> 6, l = t & 63;
  const int lr = l & 15, lk = l >> 4;
  const int bh = blockIdx.x;
  const int b = bh >> 4, h = bh & 15;

  for (int i = t; i < 64 * 64; i += 512) ((float*)Msh)[i] = 0.f;
  __syncthreads();

  // ---- phase 1: M[d][d'] = sum_s K[s,d] * V[s,d'] ----
  {
    f32x4 acc[4][4] = {};
    const unsigned short* Kbase = KVt + (size_t)(h * 128) * 8192 + b * 2048;
    const unsigned short* Vbase = Kbase + (size_t)64 * 8192;
    const int sbeg = w * 256;
    for (int s0 = sbeg; s0 < sbeg + 256; s0 += 32) {
      bf16x8 af[4], bfv[4];
#pragma unroll
      for (int mi = 0; mi < 4; ++mi)
        af[mi] = *(const bf16x8*)(Kbase + (size_t)(mi * 16 + lr) * 8192 + s0 + lk * 8);
#pragma unroll
      for (int ni = 0; ni < 4; ++ni)
        bfv[ni] = *(const bf16x8*)(Vbase + (size_t)(ni * 16 + lr) * 8192 + s0 + lk * 8);
#pragma unroll
      for (int mi = 0; mi < 4; ++mi)
#pragma unroll
        for (int ni = 0; ni < 4; ++ni)
          acc[mi][ni] = __builtin_amdgcn_mfma_f32_16x16x32_bf16(af[mi], bfv[ni], acc[mi][ni], 0, 0, 0);
    }
#pragma unroll
    for (int mi = 0; mi < 4; ++mi)
#pragma unroll
      for (int ni = 0; ni < 4; ++ni)
#pragma unroll
        for (int r = 0; r < 4; ++r)
          atomicAdd(&Msh[mi * 16 + lk * 4 + r][ni * 16 + lr], acc[mi][ni][r]);
  }
  __syncthreads();

  // ---- convert: Mt[n][k] = bf16(SCALE * M[k][n]) ----
  for (int i = t; i < 64 * 64; i += 512) {
    int n = i >> 6, k = i & 63;
    Mt[n][k] = f2bf(Msh[k][n] * SCALE_F);
  }
  __syncthreads();

  // ---- phase 2: values[s][d'] = sum_k Q[s,k] * (SCALE*M)[k][d'] ----
  {
    bf16x8 bm[2][4];
#pragma unroll
    for (int ks = 0; ks < 2; ++ks)
#pragma unroll
      for (int ni = 0; ni < 4; ++ni)
        bm[ks][ni] = *(const bf16x8*)(&Mt[ni * 16 + lr][ks * 32 + lk * 8]);

    const unsigned short* Qb = Qbuf + (size_t)(b * 2048) * 1024 + h * 64;
    unsigned short* Ob = Vals + (size_t)(b * 2048) * 1024 + h * 64;
    const int sbeg = w * 256;
    for (int m0 = sbeg; m0 < sbeg + 256; m0 += 16) {
      f32x4 acc[4] = {};
      bf16x8 a0 = *(const bf16x8*)(Qb + (size_t)(m0 + lr) * 1024 + lk * 8);
      bf16x8 a1 = *(const bf16x8*)(Qb + (size_t)(m0 + lr) * 1024 + 32 + lk * 8);
#pragma unroll
      for (int ni = 0; ni < 4; ++ni) {
        acc[ni] = __builtin_amdgcn_mfma_f32_16x16x32_bf16(a0, bm[0][ni], acc[ni], 0, 0, 0);
        acc[ni] = __builtin_amdgcn_mfma_f32_16x16x32_bf16(a1, bm[1][ni], acc[ni], 0, 0, 0);
      }
#pragma unroll
      for (int ni = 0; ni < 4; ++ni)
#pragma unroll
        for (int r = 0; r < 4; ++r)
          Ob[(size_t)(m0 + lk * 4 + r) * 1024 + ni * 16 + lr] = f2bf(acc[ni][r]);
    }
  }
}

// ---------------- launch ----------------
extern "C" void kernel_launch(void* const* d_in, const int* in_sizes, int n_in,
                              void* d_out, int out_size, void* d_ws, size_t ws_size,
                              hipStream_t stream) {
  const float* x    = (const float*)d_in[0];   // [4,2048,1024]
  const float* wqkv = (const float*)d_in[1];   // [3072,1024]
  const float* wo   = (const float*)d_in[2];   // [1024,1024]
  float* out = (float*)d_out;                  // [4,2048,1024] fp32

  char* ws = (char*)d_ws;
  unsigned short* xb   = (unsigned short*)(ws);                      // 16MB  [8192][1024]
  unsigned short* wq   = (unsigned short*)(ws + 16777216);           // 2MB   [1024][1024]
  unsigned short* wkv  = (unsigned short*)(ws + 18874368);           // 4MB   [2048][1024]
  unsigned short* wob  = (unsigned short*)(ws + 23068672);           // 2MB   [1024][1024]
  unsigned short* Qbuf = (unsigned short*)(ws + 25165824);           // 16MB  [8192][1024]
  unsigned short* KVt  = (unsigned short*)(ws + 41943040);           // 32MB  [2048][8192]
  unsigned short* Vals = (unsigned short*)(ws + 75497472);           // 16MB  [8192][1024]
  // total 92,274,688 bytes

  // converts
  cvt_plain<<<2048, 256, 0, stream>>>(x, xb, 8388608L);
  cvt_plain<<<1024, 256, 0, stream>>>(wo, wob, 1048576L);
  cvt_wq  <<<1024, 256, 0, stream>>>(wqkv, wq);
  cvt_wkv <<<2048, 256, 0, stream>>>(wqkv, wkv);

  // Q projection: Qbuf = xb * wq^T       (M=8192, N=1024, K=1024)
  gemm_bt<false><<<dim3(8, 64), 256, 0, stream>>>(xb, wq, (void*)Qbuf, 8192, 1024, 1024);
  // KV projection transposed: KVt = wkv * xb^T   (M=2048, N=8192, K=1024)
  gemm_bt<false><<<dim3(64, 16), 256, 0, stream>>>(wkv, xb, (void*)KVt, 2048, 8192, 1024);
  // fused attention (reassociated): Vals = SCALE * Q * (K^T V)
  attn_fused<<<64, 512, 0, stream>>>(Qbuf, KVt, Vals);
  // output projection: out = Vals * wob^T  (M=8192, N=1024, K=1024), fp32 out
  gemm_bt<true><<<dim3(8, 64), 256, 0, stream>>>(Vals, wob, (void*)out, 8192, 1024, 1024);
}

// Round 2
// 190.969 us; speedup vs baseline: 1.1211x; 1.1211x over previous
//
#include <hip/hip_runtime.h>
#include <hip/hip_bf16.h>
#include <cstdint>

// B=4, S=2048, E=1024, H=16, D=64, SCALE = 1/8
#define SCALE_F 0.125f

typedef __attribute__((ext_vector_type(8))) short bf16x8;
typedef __attribute__((ext_vector_type(4))) float f32x4;
typedef __attribute__((ext_vector_type(4))) unsigned short u16x4;
typedef __attribute__((ext_vector_type(8))) unsigned short u16x8;

typedef const __attribute__((address_space(1))) void glb_void;
typedef __attribute__((address_space(3))) void lds_void;

static __device__ __forceinline__ unsigned short f2bf(float f) {
  unsigned u = __builtin_bit_cast(unsigned, f);
  u = (u + 0x7fffu + ((u >> 16) & 1u)) >> 16;
  return (unsigned short)u;
}
static __device__ __forceinline__ float bf2f(unsigned short s) {
  unsigned u = ((unsigned)s) << 16;
  return __builtin_bit_cast(float, u);
}

// ---------------- converts ----------------
__global__ __launch_bounds__(256) void cvt_plain(const float* __restrict__ in,
                                                 unsigned short* __restrict__ out, long n) {
  long i = ((long)blockIdx.x * blockDim.x + threadIdx.x) * 4;
  long stride = (long)gridDim.x * blockDim.x * 4;
  for (; i < n; i += stride) {
    float4 v = *(const float4*)(in + i);
    u16x4 o = { f2bf(v.x), f2bf(v.y), f2bf(v.z), f2bf(v.w) };
    *(u16x4*)(out + i) = o;
  }
}

// wk/wv gather: row<1024 -> wk[row] = wqkv[h*192+64+k]; else wv[row-1024] = wqkv[h*192+128+k]
__global__ __launch_bounds__(256) void cvt_kv(const float* __restrict__ wqkv,
                                              unsigned short* __restrict__ wk,
                                              unsigned short* __restrict__ wv) {
  int row = blockIdx.x;            // 0..2047
  int part = row >> 10;            // 0 -> K, 1 -> V
  int local = row & 1023;
  int h = local >> 6, k = local & 63;
  const float* src = wqkv + (size_t)(h * 192 + 64 + part * 64 + k) * 1024 + threadIdx.x * 4;
  unsigned short* dst = (part == 0 ? wk : wv) + (size_t)local * 1024 + threadIdx.x * 4;
  float4 v = *(const float4*)src;
  u16x4 o = { f2bf(v.x), f2bf(v.y), f2bf(v.z), f2bf(v.w) };
  *(u16x4*)dst = o;
}

// transpose+cvt: out[c0+c][r0+r] = bf16(in[srcRow(r0+r)][c0+c]); srcRow(r) = (r>>6)*blk + (r&63)
// in: fp32, row length 1024. out: bf16 [1024][ldo]
__global__ __launch_bounds__(256) void transpose_cvt(const float* __restrict__ in,
                                                     unsigned short* __restrict__ out,
                                                     int ldo, int blk) {
  __shared__ unsigned short lds[64][72];   // 72 keeps rows 16B-aligned
  const int t = threadIdx.x;
  const int r0 = blockIdx.x * 64, c0 = blockIdx.y * 64;
#pragma unroll
  for (int pass = 0; pass < 4; ++pass) {
    int r = pass * 16 + (t >> 4);
    int c = (t & 15) * 4;
    int gr = r0 + r;
    int srcRow = (gr >> 6) * blk + (gr & 63);
    float4 v = *(const float4*)(in + (size_t)srcRow * 1024 + c0 + c);
    lds[c + 0][r] = f2bf(v.x);
    lds[c + 1][r] = f2bf(v.y);
    lds[c + 2][r] = f2bf(v.z);
    lds[c + 3][r] = f2bf(v.w);
  }
  __syncthreads();
#pragma unroll
  for (int pass = 0; pass < 2; ++pass) {
    int rr = pass * 32 + (t >> 3);   // out-row within tile (= source col)
    int cc = (t & 7) * 8;            // out-col within tile (= source row)
    *(u16x8*)(out + (size_t)(c0 + rr) * ldo + r0 + cc) = *(const u16x8*)&lds[rr][cc];
  }
}

// sum P bf16 partials: out[b*n1+e] = bf16( sum_p in[(b*P+p)*n1 + e] )
__global__ __launch_bounds__(256) void reduce_bf16(const unsigned short* __restrict__ in,
                                                   unsigned short* __restrict__ out,
                                                   int P, long n1, int nb) {
  long total = (long)nb * n1;
  long i = ((long)blockIdx.x * 256 + threadIdx.x) * 8;
  long stride = (long)gridDim.x * 256 * 8;
  for (; i < total; i += stride) {
    long b = i / n1, e = i - b * n1;
    float s[8] = {0.f, 0.f, 0.f, 0.f, 0.f, 0.f, 0.f, 0.f};
    for (int p = 0; p < P; ++p) {
      u16x8 v = *(const u16x8*)(in + (b * P + p) * n1 + e);
#pragma unroll
      for (int j = 0; j < 8; ++j) s[j] += bf2f(v[j]);
    }
    u16x8 o;
#pragma unroll
    for (int j = 0; j < 8; ++j) o[j] = f2bf(s[j]);
    *(u16x8*)(out + i) = o;
  }
}

// ---------------- generic m97-style bt GEMM with batch/split-K ----------------
// C[m][n] = sum_k A[m][k] * B[n][k]; blockIdx.z -> (bb = z/PSPLIT, pp = z%PSPLIT)
// A += bb*aB + pp*aP (elements); same for B, C. Tiles: 128x128, BK=32.
template<bool F32OUT>
__global__ __launch_bounds__(256) void gemm_bt(const unsigned short* __restrict__ A, int lda,
                                               long aB, long aP,
                                               const unsigned short* __restrict__ Bm, int ldb,
                                               long bB, long bP,
                                               void* __restrict__ Cv, int ldc,
                                               long cB, long cP,
                                               int K, int psplit) {
  __shared__ __align__(16) unsigned short Ash[128 * 32];
  __shared__ __align__(16) unsigned short Bsh[128 * 32];
  const int z = blockIdx.z;
  const int bb = z / psplit, pp = z % psplit;
  A  += (size_t)bb * aB + (size_t)pp * aP;
  Bm += (size_t)bb * bB + (size_t)pp * bP;
  const int t = threadIdx.x;
  const int w = t >> 6, l = t & 63;
  const int lr = l & 15, lk = l >> 4;
  const int m0 = blockIdx.y * 128, n0 = blockIdx.x * 128;
  const int wr = (w >> 1) * 64, wc = (w & 1) * 64;
  f32x4 acc[4][4] = {};

  for (int k0 = 0; k0 < K; k0 += 32) {
#pragma unroll
    for (int i = 0; i < 2; ++i) {
      const int c = i * 256 + t;
      const int row = c >> 2, kc = (c & 3) << 3;
      __builtin_amdgcn_global_load_lds(
          (glb_void*)(A + (size_t)(m0 + row) * lda + k0 + kc),
          (lds_void*)(Ash + i * 2048 + w * 512), 16, 0, 0);
      __builtin_amdgcn_global_load_lds(
          (glb_void*)(Bm + (size_t)(n0 + row) * ldb + k0 + kc),
          (lds_void*)(Bsh + i * 2048 + w * 512), 16, 0, 0);
    }
    __syncthreads();

    bf16x8 af[4], bfv[4];
#pragma unroll
    for (int mi = 0; mi < 4; ++mi)
      af[mi] = *(const bf16x8*)(Ash + (wr + mi * 16 + lr) * 32 + lk * 8);
#pragma unroll
    for (int ni = 0; ni < 4; ++ni)
      bfv[ni] = *(const bf16x8*)(Bsh + (wc + ni * 16 + lr) * 32 + lk * 8);
#pragma unroll
    for (int mi = 0; mi < 4; ++mi)
#pragma unroll
      for (int ni = 0; ni < 4; ++ni)
        acc[mi][ni] = __builtin_amdgcn_mfma_f32_16x16x32_bf16(af[mi], bfv[ni], acc[mi][ni], 0, 0, 0);
    __syncthreads();
  }

#pragma unroll
  for (int mi = 0; mi < 4; ++mi)
#pragma unroll
    for (int ni = 0; ni < 4; ++ni)
#pragma unroll
      for (int r = 0; r < 4; ++r) {
        const size_t row = (size_t)(m0 + wr + mi * 16 + lk * 4 + r);
        const size_t col = (size_t)(n0 + wc + ni * 16 + lr);
        if constexpr (F32OUT)
          ((float*)Cv)[(size_t)bb * cB + (size_t)pp * cP + row * ldc + col] = acc[mi][ni][r];
        else
          ((unsigned short*)Cv)[(size_t)bb * cB + (size_t)pp * cP + row * ldc + col] = f2bf(acc[mi][ni][r]);
      }
}

// ---------------- Mt[b,h][d'][k] = bf16( SCALE * sum_e T1_b[h*64+k][e] * wv[h*64+d'][e] ) ----------------
__global__ __launch_bounds__(256) void make_mt(const unsigned short* __restrict__ T1,
                                               const unsigned short* __restrict__ wv,
                                               unsigned short* __restrict__ Mt) {
  __shared__ float Msh[64][64];
  const int t = threadIdx.x;
  const int w = t >> 6, l = t & 63;
  const int lr = l & 15, lk = l >> 4;
  const int bh = blockIdx.x;
  const int b = bh >> 4, h = bh & 15;

  for (int i = t; i < 64 * 64; i += 256) ((float*)Msh)[i] = 0.f;
  __syncthreads();

  const unsigned short* Ab = T1 + (size_t)b * 1048576 + (size_t)(h * 64) * 1024;
  const unsigned short* Bb = wv + (size_t)(h * 64) * 1024;
  f32x4 acc[4][4] = {};
  const int ebeg = w * 256;
  for (int e0 = ebeg; e0 < ebeg + 256; e0 += 32) {
    bf16x8 af[4], bfv[4];
#pragma unroll
    for (int mi = 0; mi < 4; ++mi)
      af[mi] = *(const bf16x8*)(Ab + (size_t)(mi * 16 + lr) * 1024 + e0 + lk * 8);
#pragma unroll
    for (int ni = 0; ni < 4; ++ni)
      bfv[ni] = *(const bf16x8*)(Bb + (size_t)(ni * 16 + lr) * 1024 + e0 + lk * 8);
#pragma unroll
    for (int mi = 0; mi < 4; ++mi)
#pragma unroll
      for (int ni = 0; ni < 4; ++ni)
        acc[mi][ni] = __builtin_amdgcn_mfma_f32_16x16x32_bf16(af[mi], bfv[ni], acc[mi][ni], 0, 0, 0);
  }
#pragma unroll
  for (int mi = 0; mi < 4; ++mi)
#pragma unroll
    for (int ni = 0; ni < 4; ++ni)
#pragma unroll
      for (int r = 0; r < 4; ++r)
        atomicAdd(&Msh[mi * 16 + lk * 4 + r][ni * 16 + lr], acc[mi][ni][r]);
  __syncthreads();

  // Mt[d'][k] = SCALE * M[k][d']
  for (int i = t; i < 64 * 64; i += 256) {
    int dp = i >> 6, k = i & 63;
    Mt[(size_t)bh * 4096 + i] = f2bf(Msh[k][dp] * SCALE_F);
  }
}

// ---------------- Amat_b[e][h*64+d'] = sum_k wqt[e][h*64+k] * Mt[b,h][d'][k] ----------------
__global__ __launch_bounds__(256) void make_amat(const unsigned short* __restrict__ wqt,
                                                 const unsigned short* __restrict__ Mt,
                                                 unsigned short* __restrict__ Amat) {
  const int t = threadIdx.x;
  const int w = t >> 6, l = t & 63;
  const int lr = l & 15, lk = l >> 4;
  const int et = blockIdx.x, h = blockIdx.y, b = blockIdx.z;
  const int e0 = et * 128 + w * 32;
  const unsigned short* Bb = Mt + (size_t)(b * 16 + h) * 4096;

  f32x4 acc[2][4] = {};
#pragma unroll
  for (int ks = 0; ks < 2; ++ks) {
    bf16x8 af[2], bfv[4];
#pragma unroll
    for (int mi = 0; mi < 2; ++mi)
      af[mi] = *(const bf16x8*)(wqt + (size_t)(e0 + mi * 16 + lr) * 1024 + h * 64 + ks * 32 + lk * 8);
#pragma unroll
    for (int ni = 0; ni < 4; ++ni)
      bfv[ni] = *(const bf16x8*)(Bb + (size_t)(ni * 16 + lr) * 64 + ks * 32 + lk * 8);
#pragma unroll
    for (int mi = 0; mi < 2; ++mi)
#pragma unroll
      for (int ni = 0; ni < 4; ++ni)
        acc[mi][ni] = __builtin_amdgcn_mfma_f32_16x16x32_bf16(af[mi], bfv[ni], acc[mi][ni], 0, 0, 0);
  }
#pragma unroll
  for (int mi = 0; mi < 2; ++mi)
#pragma unroll
    for (int ni = 0; ni < 4; ++ni)
#pragma unroll
      for (int r = 0; r < 4; ++r)
        Amat[(size_t)b * 1048576 + (size_t)(e0 + mi * 16 + lk * 4 + r) * 1024 + h * 64 + ni * 16 + lr]
            = f2bf(acc[mi][ni][r]);
}

// ---------------- launch ----------------
extern "C" void kernel_launch(void* const* d_in, const int* in_sizes, int n_in,
                              void* d_out, int out_size, void* d_ws, size_t ws_size,
                              hipStream_t stream) {
  const float* x    = (const float*)d_in[0];   // [4,2048,1024]
  const float* wqkv = (const float*)d_in[1];   // [3072,1024]
  const float* wo   = (const float*)d_in[2];   // [1024,1024]
  float* out = (float*)d_out;                  // [4,2048,1024] fp32

  char* ws = (char*)d_ws;
  const size_t MB = 1048576;
  unsigned short* xb   = (unsigned short*)(ws + 0);        // 16MB [8192][1024]
  unsigned short* xT   = (unsigned short*)(ws + 16 * MB);  // 16MB [1024][8192]
  unsigned short* wqt  = (unsigned short*)(ws + 32 * MB);  // 2MB  [1024 e][1024 i]  (Wq^T)
  unsigned short* wk   = (unsigned short*)(ws + 34 * MB);  // 2MB  [1024][1024]
  unsigned short* wv   = (unsigned short*)(ws + 36 * MB);  // 2MB  [1024][1024]
  unsigned short* wob  = (unsigned short*)(ws + 38 * MB);  // 2MB  [1024][1024]
  unsigned short* Gp   = (unsigned short*)(ws + 40 * MB);  // 16MB [4b][2p][1024][1024]
  unsigned short* G    = (unsigned short*)(ws + 56 * MB);  // 8MB  [4b][1024][1024] (symmetric)
  unsigned short* T1p  = (unsigned short*)(ws + 64 * MB);  // 16MB [4b][2p][1024][1024]
  unsigned short* T1   = (unsigned short*)(ws + 80 * MB);  // 8MB  [4b][1024][1024]  -> peak 88MB
  // reuse dead regions:
  unsigned short* Mt   = (unsigned short*)(ws + 40 * MB);  // 512KB [64 bh][64][64]
  unsigned short* Amat = (unsigned short*)(ws + 41 * MB);  // 8MB  [4b][1024 e][1024 i]
  unsigned short* Wp   = (unsigned short*)(ws + 49 * MB);  // 16MB (over G/T1p, dead by then)
  unsigned short* Weff = (unsigned short*)(ws + 66 * MB);  // 8MB  [4b][1024 j][1024 e] (W_eff^T)

  const long M1 = 1048576;

  // converts / transposes
  cvt_plain<<<2048, 256, 0, stream>>>(x, xb, 8388608L);
  transpose_cvt<<<dim3(128, 16), 256, 0, stream>>>(x, xT, 8192, 64);     // xT[e][b*2048+s]
  transpose_cvt<<<dim3(16, 16), 256, 0, stream>>>(wqkv, wqt, 1024, 192); // wqt[e][h*64+k]
  cvt_kv<<<2048, 256, 0, stream>>>(wqkv, wk, wv);
  cvt_plain<<<1024, 256, 0, stream>>>(wo, wob, 1048576L);

  // G_b = x_b^T x_b  (split-K x2): Gp[z=(b,p)] = xT[:, z*1024 .. +1024] dotted
  gemm_bt<false><<<dim3(8, 8, 8), 256, 0, stream>>>(xT, 8192, 2048, 1024,
                                                    xT, 8192, 2048, 1024,
                                                    (void*)Gp, 1024, 2 * M1, M1, 1024, 2);
  reduce_bf16<<<2048, 256, 0, stream>>>(Gp, G, 2, M1, 4);

  // T1_b = wk @ G_b  (G symmetric -> bt form OK), split-K x2
  gemm_bt<false><<<dim3(8, 8, 8), 256, 0, stream>>>(wk, 1024, 0, 512,
                                                    G, 1024, M1, 512,
                                                    (void*)T1p, 1024, 2 * M1, M1, 512, 2);
  reduce_bf16<<<2048, 256, 0, stream>>>(T1p, T1, 2, M1, 4);

  // Mt[b,h] = SCALE * (T1_bh @ wv_h^T)^T
  make_mt<<<64, 256, 0, stream>>>(T1, wv, Mt);

  // Amat_b = Wq^T * blockdiag(SCALE*M_b)
  make_amat<<<dim3(8, 16, 4), 256, 0, stream>>>(wqt, Mt, Amat);

  // Weff_b[j][e] = sum_i wo[j][i] * Amat_b[e][i], split-K x2
  gemm_bt<false><<<dim3(8, 8, 8), 256, 0, stream>>>(wob, 1024, 0, 512,
                                                    Amat, 1024, M1, 512,
                                                    (void*)Wp, 1024, 2 * M1, M1, 512, 2);
  reduce_bf16<<<2048, 256, 0, stream>>>(Wp, Weff, 2, M1, 4);

  // out_b = x_b @ Weff_b^T  (fp32 out)
  gemm_bt<true><<<dim3(8, 16, 4), 256, 0, stream>>>(xb, 1024, 2048 * 1024L, 0,
                                                    Weff, 1024, M1, 0,
                                                    (void*)out, 1024, 2048 * 1024L, 0, 1024, 1);
}